// Round 23
// baseline (249.631 us; speedup 1.0000x reference)
//
#include <hip/hip_runtime.h>
#include <cmath>

#define DIM 16
#define VOCAB 18
#define TLEN 2048
#define NBLK (TLEN / 64)
#define TWO_LOG2E 2.8853900817779268f  // 2*log2(e)

// Load float input element idx, from either a bf16 or f32 device buffer.
__device__ __forceinline__ float ldf(const void* p, int idx, int isbf) {
    if (isbf) {
        unsigned int w = ((const unsigned short*)p)[idx];
        return __uint_as_float(w << 16);
    }
    return ((const float*)p)[idx];
}

// ---------------------------------------------------------------------------
// Detector 1: token width. int64 tokens (0..17) have all odd 32-bit words 0.
// ---------------------------------------------------------------------------
__global__ void detect_tok(const int* __restrict__ x32, int* __restrict__ flag) {
    int v = 0;
    for (int j = threadIdx.x; j < 4096; j += 64) v |= x32[2 * j + 1];
    unsigned long long any = __ballot(v != 0);
    if (threadIdx.x == 0) flag[0] = (any == 0ULL) ? 1 : 0;
}

// ---------------------------------------------------------------------------
// Detector 2: float width. bf16 words of N(0,1) data have exponent in
// [90,140]; f32 lo-mantissa words are uniform random -> certain failure.
// ---------------------------------------------------------------------------
__global__ void detect_f(const unsigned short* __restrict__ emb16,
                         int* __restrict__ flag) {
    int bad = 0;
    for (int j = threadIdx.x; j < VOCAB * DIM; j += 64) {
        unsigned short w = emb16[j];
        int e = (w >> 7) & 0xFF;
        if (!((e >= 90 && e <= 140) || (w & 0x7FFF) == 0)) bad = 1;
    }
    unsigned long long anybad = __ballot(bad);
    if (threadIdx.x == 0) flag[1] = (anybad == 0ULL) ? 1 : 0;
}

// ---------------------------------------------------------------------------
// Setup: wtab[v][k] = sum_d emb[v,d] * W_w[k,d] + W_b[k]   (18 x 16, f32)
// ---------------------------------------------------------------------------
__global__ void wtab_kernel(const void* __restrict__ emb,
                            const void* __restrict__ W_w,
                            const void* __restrict__ W_b,
                            const int* __restrict__ flag,
                            float* __restrict__ wtab) {
    int tid = threadIdx.x;
    int isbf = flag[1];
    if (tid < VOCAB * DIM) {
        int v = tid >> 4, kk = tid & 15;
        float s = ldf(W_b, kk, isbf);
#pragma unroll
        for (int d = 0; d < DIM; ++d)
            s = fmaf(ldf(emb, v * DIM + d, isbf), ldf(W_w, kk * DIM + d, isbf), s);
        wtab[tid] = s;
    }
}

#define WSTR 19   // wtabT row stride: spreads 16 lanes over 16 banks
#define SSTR 68   // slab element stride (16B aligned; groups 4 banks apart)

// ---------------------------------------------------------------------------
// Main RNN kernel: R22-validated core, DUAL-PIPELINED (2 element sets/wave).
// 16 lanes per element, 4 elements per set, sets A and B time-interleaved:
// B's issue fills A's exp2/rcp latency tail (and vice versa), converting
// the 78-cyc/step serial-chain stall into useful work.
//   S_k = scale*(wtab[tok][k]+rowsumU[k]) + sum_j (-2*scale*U[k][dj])*r[dj]
//   r' = 1/(2^S+1)    (h = 1-2r folded into weights)
// 128 thr/block (2 waves, 16 elements), 256 blocks -> 512 waves.
// ---------------------------------------------------------------------------
__global__ __launch_bounds__(128) void rnn_kernel(const int* __restrict__ x32,
                                                  const int* __restrict__ flag,
                                                  const float* __restrict__ wtab_g,
                                                  const void* __restrict__ U_w,
                                                  const void* __restrict__ head_w,
                                                  const void* __restrict__ head_b,
                                                  float* __restrict__ out) {
    __shared__ float wtabT[16 * WSTR];  // [k][v] stride 19, folded+prescaled
    __shared__ float sU[DIM * DIM];
    __shared__ float lds_h[16][DIM];
    __shared__ int slab[2][16 * SSTR];  // token slabs, per-element slices

    const int tid = threadIdx.x;
    const int is64 = __builtin_amdgcn_readfirstlane(flag[0]);
    const int isbf = __builtin_amdgcn_readfirstlane(flag[1]);

    // Strided fills (never the guarded-single-store bug again).
    for (int i = tid; i < 16 * WSTR; i += 128) {
        int r = i / WSTR, v = i - r * WSTR;
        float val = 0.0f;
        if (v < VOCAB) {
            float rs = 0.0f;
#pragma unroll
            for (int d = 0; d < DIM; ++d) rs += ldf(U_w, r * DIM + d, isbf);
            val = (wtab_g[v * DIM + r] + rs) * TWO_LOG2E;  // transposed+folded
        }
        wtabT[i] = val;
    }
    for (int i = tid; i < DIM * DIM; i += 128) sU[i] = ldf(U_w, i, isbf);
    __syncthreads();  // the only block-wide barrier until the head

    const int lane = tid & 63;
    const int wave = tid >> 6;       // 0..1
    const int g16 = lane >> 4;       // group within wave
    const int k = lane & 15;         // output dim owned by this lane
    const int eA = (wave << 3) | g16;       // set-A element within block
    const int eB = eA + 4;                  // set-B element within block
    const int gelemA = (blockIdx.x << 4) | eA;
    const int gelemB = (blockIdx.x << 4) | eB;

    // Probe DPP ror direction (validated R12-R22).
    int p = __builtin_amdgcn_mov_dpp(k, 0x121, 0xF, 0xF, true);
    int c = (p - k) & 15;

    // ur2[j] = -2 * scale * U[k][(k + j*c) & 15] — shared by both sets.
    float ur2[16];
#pragma unroll
    for (int j = 0; j < 16; ++j)
        ur2[j] = sU[(k << 4) | ((k + j * c) & 15)] * (-2.0f * TWO_LOG2E);

    const int wb = k * WSTR;

    const size_t tokbaseA = (size_t)gelemA * TLEN + (k << 2);
    const size_t tokbaseB = (size_t)gelemB * TLEN + (k << 2);

    int* curA = &slab[0][eA * SSTR];
    int* nxtA = &slab[1][eA * SSTR];
    int* curB = &slab[0][eB * SSTR];
    int* nxtB = &slab[1][eB * SSTR];

#define LOADG(G, B, TOKBASE)                                                  \
    {                                                                         \
        if (is64) {                                                           \
            const int* pp = x32 + (((TOKBASE) + ((size_t)(B) << 6)) << 1);    \
            int4 a = *(const int4*)pp;                                        \
            int4 bq = *(const int4*)(pp + 4);                                 \
            G = make_int4(a.x, a.z, bq.x, bq.z);                              \
        } else {                                                              \
            G = *(const int4*)(x32 + (TOKBASE) + ((size_t)(B) << 6));         \
        }                                                                     \
    }

    // Prologue: slab0 <- blk0 for both sets; gcur <- blk1; prime pipelines.
    int4 g0;
    LOADG(g0, 0, tokbaseA)
    *(int4*)(curA + (k << 2)) = g0;
    LOADG(g0, 0, tokbaseB)
    *(int4*)(curB + (k << 2)) = g0;
    int4 gcurA, gcurB;
    LOADG(gcurA, 1, tokbaseA)
    LOADG(gcurB, 1, tokbaseB)

    int4 tA0 = *(const int4*)(curA + 0);
    int4 tnA = *(const int4*)(curA + 4);
    float wqA0 = wtabT[wb + tA0.x], wqA1 = wtabT[wb + tA0.y];
    float wqA2 = wtabT[wb + tA0.z], wqA3 = wtabT[wb + tA0.w];
    int4 tB0 = *(const int4*)(curB + 0);
    int4 tnB = *(const int4*)(curB + 4);
    float wqB0 = wtabT[wb + tB0.x], wqB1 = wtabT[wb + tB0.y];
    float wqB2 = wtabT[wb + tB0.z], wqB3 = wtabT[wb + tB0.w];

    float rstA = 0.5f, rstB = 0.5f;  // r-state for h0 = 0

// One step of one set. RST = that set's state; W = this step's wtab value;
// TN = token 4 ahead; WN = its wtab value (consumed next group).
#define STEP(RST, W, TN, WN)                                                   \
    {                                                                          \
        WN = wtabT[wb + (TN)];                                                 \
        float a0 = fmaf(ur2[0], RST, W);                                       \
        float a1, a2, a3;                                                      \
        asm("s_nop 1\n\t"                                                      \
            "v_mul_f32_dpp %[a1], %[r], %[u1] row_ror:1 row_mask:0xf bank_mask:0xf\n\t"  \
            "v_mul_f32_dpp %[a2], %[r], %[u2] row_ror:2 row_mask:0xf bank_mask:0xf\n\t"  \
            "v_mul_f32_dpp %[a3], %[r], %[u3] row_ror:3 row_mask:0xf bank_mask:0xf\n\t"  \
            "v_fmac_f32_dpp %[a0], %[r], %[u4] row_ror:4 row_mask:0xf bank_mask:0xf\n\t" \
            "v_fmac_f32_dpp %[a1], %[r], %[u5] row_ror:5 row_mask:0xf bank_mask:0xf\n\t" \
            "v_fmac_f32_dpp %[a2], %[r], %[u6] row_ror:6 row_mask:0xf bank_mask:0xf\n\t" \
            "v_fmac_f32_dpp %[a3], %[r], %[u7] row_ror:7 row_mask:0xf bank_mask:0xf\n\t" \
            "v_fmac_f32_dpp %[a0], %[r], %[u8] row_ror:8 row_mask:0xf bank_mask:0xf\n\t" \
            "v_fmac_f32_dpp %[a1], %[r], %[u9] row_ror:9 row_mask:0xf bank_mask:0xf\n\t" \
            "v_fmac_f32_dpp %[a2], %[r], %[u10] row_ror:10 row_mask:0xf bank_mask:0xf\n\t" \
            "v_fmac_f32_dpp %[a3], %[r], %[u11] row_ror:11 row_mask:0xf bank_mask:0xf\n\t" \
            "v_fmac_f32_dpp %[a0], %[r], %[u12] row_ror:12 row_mask:0xf bank_mask:0xf\n\t" \
            "v_fmac_f32_dpp %[a1], %[r], %[u13] row_ror:13 row_mask:0xf bank_mask:0xf\n\t" \
            "v_fmac_f32_dpp %[a2], %[r], %[u14] row_ror:14 row_mask:0xf bank_mask:0xf\n\t" \
            "v_fmac_f32_dpp %[a3], %[r], %[u15] row_ror:15 row_mask:0xf bank_mask:0xf"     \
            : [a0] "+v"(a0), [a1] "=&v"(a1), [a2] "=&v"(a2), [a3] "=&v"(a3)    \
            : [r] "v"(RST), [u1] "v"(ur2[1]), [u2] "v"(ur2[2]),                \
              [u3] "v"(ur2[3]), [u4] "v"(ur2[4]), [u5] "v"(ur2[5]),            \
              [u6] "v"(ur2[6]), [u7] "v"(ur2[7]), [u8] "v"(ur2[8]),            \
              [u9] "v"(ur2[9]), [u10] "v"(ur2[10]), [u11] "v"(ur2[11]),        \
              [u12] "v"(ur2[12]), [u13] "v"(ur2[13]), [u14] "v"(ur2[14]),      \
              [u15] "v"(ur2[15]));                                             \
        float S = (a0 + a1) + (a2 + a3);                                       \
        RST = __builtin_amdgcn_rcpf(__builtin_amdgcn_exp2f(S) + 1.0f);         \
    }

    for (int b = 0; b < NBLK; ++b) {
        *(int4*)(nxtA + (k << 2)) = gcurA;
        *(int4*)(nxtB + (k << 2)) = gcurB;
        const int nb2 = (b + 2 < NBLK) ? b + 2 : NBLK - 1;
        LOADG(gcurA, nb2, tokbaseA)
        LOADG(gcurB, nb2, tokbaseB)

#pragma unroll
        for (int gi = 0; gi < 16; ++gi) {
            // Token batches for group gi+2 (>= 4 steps of slack), both sets.
            int4 tCA = (gi < 14) ? *(const int4*)(curA + ((gi + 2) << 2))
                                 : *(const int4*)(nxtA + ((gi - 14) << 2));
            int4 tCB = (gi < 14) ? *(const int4*)(curB + ((gi + 2) << 2))
                                 : *(const int4*)(nxtB + ((gi - 14) << 2));

            float wnA0, wnA1, wnA2, wnA3, wnB0, wnB1, wnB2, wnB3;
            // Interleaved: B's issue fills A's trans latency, and vice versa.
            STEP(rstA, wqA0, tnA.x, wnA0)
            STEP(rstB, wqB0, tnB.x, wnB0)
            STEP(rstA, wqA1, tnA.y, wnA1)
            STEP(rstB, wqB1, tnB.y, wnB1)
            STEP(rstA, wqA2, tnA.z, wnA2)
            STEP(rstB, wqB2, tnB.z, wnB2)
            STEP(rstA, wqA3, tnA.w, wnA3)
            STEP(rstB, wqB3, tnB.w, wnB3)

            wqA0 = wnA0; wqA1 = wnA1; wqA2 = wnA2; wqA3 = wnA3;
            wqB0 = wnB0; wqB1 = wnB1; wqB2 = wnB2; wqB3 = wnB3;
            tnA = tCA;
            tnB = tCB;
        }
        int* tmp = curA; curA = nxtA; nxtA = tmp;
        tmp = curB; curB = nxtB; nxtB = tmp;
    }

    // Head: h = 1 - 2r; out[b,v] = h . head_w[v,:] + head_b[v], f32 store.
    lds_h[eA][k] = fmaf(-2.0f, rstA, 1.0f);
    lds_h[eB][k] = fmaf(-2.0f, rstB, 1.0f);
    __syncthreads();

    for (int i = tid; i < 16 * VOCAB; i += 128) {
        int ee = i / VOCAB;
        int v = i - ee * VOCAB;
        float s = ldf(head_b, v, isbf);
#pragma unroll
        for (int d = 0; d < DIM; ++d)
            s = fmaf(lds_h[ee][d], ldf(head_w, (v << 4) + d, isbf), s);
        out[(size_t)((blockIdx.x << 4) | ee) * VOCAB + v] = s;
    }
}

extern "C" void kernel_launch(void* const* d_in, const int* in_sizes, int n_in,
                              void* d_out, int out_size, void* d_ws, size_t ws_size,
                              hipStream_t stream) {
    const int* x = (const int*)d_in[0];
    const void* emb = d_in[1];
    const void* W_w = d_in[2];
    const void* W_b = d_in[3];
    const void* U_w = d_in[4];
    const void* head_w = d_in[5];
    const void* head_b = d_in[6];

    float* wtab = (float*)d_ws;              // 288 floats
    int* flag = (int*)((char*)d_ws + 4096);  // [0]=tok is64, [1]=floats are bf16

    detect_tok<<<1, 64, 0, stream>>>(x, flag);
    detect_f<<<1, 64, 0, stream>>>((const unsigned short*)emb, flag);
    wtab_kernel<<<1, 320, 0, stream>>>(emb, W_w, W_b, flag, wtab);
    rnn_kernel<<<256, 128, 0, stream>>>(x, flag, wtab, U_w, head_w, head_b,
                                        (float*)d_out);
}